// Round 6
// baseline (11923.315 us; speedup 1.0000x reference)
//
#include <hip/hip_runtime.h>
#include <cmath>

#define B 128
#define T 128
#define H 512
#define TGT 32
#define SCOPE_AGENT __HIP_MEMORY_SCOPE_AGENT

// ws: dstate [2 parity][4 layer][B][H] f32 (2MB) | ctr 16KB (128B-strided) | l0/G1 [T][B][1024] f32 (64MB)
struct Args {
  const float *x, *eWih0, *eWhh0, *eWih1, *eWhh1, *ebih, *ebhh;
  const float *dWih0, *dWihr, *dWhh, *dbih, *dbhh, *linW, *linb;
  float *dst; float *l0; unsigned *ctr; float *out;
};

__global__ void kinit(float* __restrict__ st, unsigned* __restrict__ ctr) {
  int idx = blockIdx.x * 256 + threadIdx.x;
  for (int i = idx; i < 4 * B * H; i += 65536) st[i] = 0.f;  // parity-0 state
  if (idx < 4096) ctr[idx] = 0u;
}

__device__ __forceinline__ float d4(float4 a, float4 b) {
  return a.x * b.x + a.y * b.y + a.z * b.z + a.w * b.w;
}
// round-4-proven sync primitives
__device__ __forceinline__ void bump(unsigned* c) {
  __syncthreads();
  if (threadIdx.x == 0) __hip_atomic_fetch_add(c, 1u, __ATOMIC_RELEASE, SCOPE_AGENT);
}
__device__ __forceinline__ void waitc(unsigned* c, unsigned t) {
  if (threadIdx.x == 0) {
    while (__hip_atomic_load(c, __ATOMIC_ACQUIRE, SCOPE_AGENT) < t)
      __builtin_amdgcn_s_sleep(2);
  }
  __syncthreads();
}

// h rows staged in 36-float chunks (16 chunks of 32 fl, stride 36)
__device__ __forceinline__ void stage_h(const float* __restrict__ g, float* __restrict__ l,
                                        int tid) {
  int bs = tid >> 5, seg = tid & 31;
  const float4* gp = (const float4*)(g + bs * H + seg * 16);
  float4* lp = (float4*)(l + bs * 576 + (seg >> 1) * 36 + (seg & 1) * 16);
  lp[0] = gp[0]; lp[1] = gp[1]; lp[2] = gp[2]; lp[3] = gp[3];
}

// ===========================================================================
// Encoder phase (E0 / E1). 256 blocks = 16 ntile(32n) x 16 btile(8b), both dirs
// interleaved fwd/bwd per step. Whh slices register-resident (128 VGPRs).
// ===========================================================================
template <bool E1P>
__device__ __forceinline__ void enc_phase(const Args& a, float* sm, int bx, int tid) {
  const int ntile = bx & 15, btile = bx >> 4;
  const int n0 = ntile * 32, b0 = btile * 8;
  const int kc = tid & 15, ng = tid >> 4;          // compute role: 2n x 32k
  const int rA = n0 + 2 * ng, rBr = rA + 1;
  const int rb = tid >> 5, rn = tid & 31;          // reduce role: (b, n)
  const float* WHH = E1P ? a.eWhh1 : a.eWhh0;
  unsigned* cf = a.ctr + ((E1P ? 32 : 0) + btile) * 32;
  unsigned* cb = a.ctr + ((E1P ? 32 : 0) + 16 + btile) * 32;
  const int LF = E1P ? 2 : 0, LB = LF + 1;
  float* HF = sm;            // 8*576
  float* HB = sm + 4608;     // 8*576
  float* PT = sm + 9216;     // 8*32*20
  float* XS = sm + 14336;    // 8*384 (E0 only)

  float4 wfA[8], wfB[8], wbA[8], wbB[8];
  {
    const float4* p;
    p = (const float4*)(WHH + (size_t)rA * H + kc * 32);
#pragma unroll
    for (int i = 0; i < 8; i++) wfA[i] = p[i];
    p = (const float4*)(WHH + (size_t)rBr * H + kc * 32);
#pragma unroll
    for (int i = 0; i < 8; i++) wfB[i] = p[i];
    p = (const float4*)(WHH + ((size_t)H + rA) * H + kc * 32);
#pragma unroll
    for (int i = 0; i < 8; i++) wbA[i] = p[i];
    p = (const float4*)(WHH + ((size_t)H + rBr) * H + kc * 32);
#pragma unroll
    for (int i = 0; i < 8; i++) wbB[i] = p[i];
  }
  float wxf[3], wxb[3], bsf = 0.f, bsb = 0.f;
  if (!E1P) {
#pragma unroll
    for (int i = 0; i < 3; i++) {
      wxf[i] = a.eWih0[(0 * H + n0 + rn) * 3 + i];
      wxb[i] = a.eWih0[(1 * H + n0 + rn) * 3 + i];
    }
    bsf = a.ebih[0 * H + n0 + rn] + a.ebhh[0 * H + n0 + rn];
    bsb = a.ebih[1 * H + n0 + rn] + a.ebhh[1 * H + n0 + rn];
    const float4* gp = (const float4*)(a.x + (size_t)b0 * 384);
    float4* lp = (float4*)XS;
#pragma unroll
    for (int i = 0; i < 3; i++) lp[tid * 3 + i] = gp[tid * 3 + i];
  }

  for (int s = 0; s < T; s++) {
    const int p = s & 1, q = 1 - p;
    // ---------------- FWD (t = s) ----------------
    if (s) waitc(cf, 16u * (unsigned)s); else __syncthreads();
    stage_h(a.dst + ((size_t)(p * 4 + LF) * B + b0) * H, HF, tid);
    float g1f = 0.f;
    if (E1P) g1f = a.l0[((size_t)s * B + (b0 + rb)) * 1024 + n0 + rn];
    __syncthreads();
    {
      const float* hb = HF + kc * 36;
      for (int b = 0; b < 8; b++) {
        const float4* h4 = (const float4*)(hb + b * 576);
        float a0 = 0.f, a1 = 0.f;
#pragma unroll
        for (int i = 0; i < 8; i++) { float4 hv = h4[i]; a0 += d4(wfA[i], hv); a1 += d4(wfB[i], hv); }
        PT[(b * 32 + 2 * ng) * 20 + kc] = a0;
        PT[(b * 32 + 2 * ng + 1) * 20 + kc] = a1;
      }
    }
    __syncthreads();
    {
      const float4* pp = (const float4*)(PT + (rb * 32 + rn) * 20);
      float4 q0 = pp[0], q1 = pp[1], q2 = pp[2], q3 = pp[3];
      float sum = ((q0.x + q0.y) + (q0.z + q0.w)) + ((q1.x + q1.y) + (q1.z + q1.w)) +
                  ((q2.x + q2.y) + (q2.z + q2.w)) + ((q3.x + q3.y) + (q3.z + q3.w));
      float pre;
      if (E1P) pre = sum + g1f;
      else {
        const float* xr = XS + rb * 384 + s * 3;
        pre = sum + bsf + xr[0] * wxf[0] + xr[1] * wxf[1] + xr[2] * wxf[2];
      }
      float o = tanhf(pre);
      a.dst[((size_t)(q * 4 + LF) * B + (b0 + rb)) * H + n0 + rn] = o;
      if (!E1P) a.l0[((size_t)s * B + (b0 + rb)) * 1024 + n0 + rn] = o;
    }
    bump(cf);
    // ---------------- BWD (t = T-1-s) ----------------
    if (s) waitc(cb, 16u * (unsigned)s); else __syncthreads();
    stage_h(a.dst + ((size_t)(p * 4 + LB) * B + b0) * H, HB, tid);
    float g1b = 0.f;
    if (E1P) g1b = a.l0[((size_t)(T - 1 - s) * B + (b0 + rb)) * 1024 + 512 + n0 + rn];
    __syncthreads();
    {
      const float* hb = HB + kc * 36;
      for (int b = 0; b < 8; b++) {
        const float4* h4 = (const float4*)(hb + b * 576);
        float a0 = 0.f, a1 = 0.f;
#pragma unroll
        for (int i = 0; i < 8; i++) { float4 hv = h4[i]; a0 += d4(wbA[i], hv); a1 += d4(wbB[i], hv); }
        PT[(b * 32 + 2 * ng) * 20 + kc] = a0;
        PT[(b * 32 + 2 * ng + 1) * 20 + kc] = a1;
      }
    }
    __syncthreads();
    {
      const float4* pp = (const float4*)(PT + (rb * 32 + rn) * 20);
      float4 q0 = pp[0], q1 = pp[1], q2 = pp[2], q3 = pp[3];
      float sum = ((q0.x + q0.y) + (q0.z + q0.w)) + ((q1.x + q1.y) + (q1.z + q1.w)) +
                  ((q2.x + q2.y) + (q2.z + q2.w)) + ((q3.x + q3.y) + (q3.z + q3.w));
      float pre;
      int t = T - 1 - s;
      if (E1P) pre = sum + g1b;
      else {
        const float* xr = XS + rb * 384 + t * 3;
        pre = sum + bsb + xr[0] * wxb[0] + xr[1] * wxb[1] + xr[2] * wxb[2];
      }
      float o = tanhf(pre);
      a.dst[((size_t)(q * 4 + LB) * B + (b0 + rb)) * H + n0 + rn] = o;
      if (!E1P) a.l0[((size_t)t * B + (b0 + rb)) * 1024 + 512 + n0 + rn] = o;
    }
    bump(cb);
  }
}

// ===========================================================================
// enc1 input projection, in-place over l0 (includes layer-1 biases).
// ===========================================================================
__device__ __forceinline__ void proj_phase(const Args& a, float* sm, int bx, int tid) {
  const int r0 = bx * 64;
  const int rg = tid >> 4, cg = tid & 15;
  for (int hh = 0; hh < 2; hh++) {
    const int rbase = r0 + hh * 32;
    __syncthreads();
    {
      int row = tid >> 3, seg = tid & 7;
      const float4* gp = (const float4*)(a.l0 + (size_t)(rbase + row) * 1024 + seg * 128);
      float4* lp = (float4*)(sm + row * 1032 + seg * 128);
#pragma unroll
      for (int i = 0; i < 32; i++) lp[i] = gp[i];
    }
    __syncthreads();
    const float4* x0 = (const float4*)(sm + (rg * 2 + 0) * 1032);
    const float4* x1 = (const float4*)(sm + (rg * 2 + 1) * 1032);
    for (int j = 0; j < 8; j++) {
      const int c0 = j * 128 + cg * 8;
      float acc0[8], acc1[8];
#pragma unroll
      for (int i = 0; i < 8; i++) { acc0[i] = 0.f; acc1[i] = 0.f; }
      const float4* w0 = (const float4*)(a.eWih1 + (size_t)c0 * 1024);
      for (int k4 = 0; k4 < 256; k4++) {
        float4 xv0 = x0[k4], xv1 = x1[k4];
#pragma unroll
        for (int cc = 0; cc < 8; cc++) {
          float4 wv = w0[cc * 256 + k4];
          acc0[cc] += d4(wv, xv0);
          acc1[cc] += d4(wv, xv1);
        }
      }
#pragma unroll
      for (int cc = 0; cc < 8; cc++) {
        int c = c0 + cc;
        float bias = a.ebih[1024 + c] + a.ebhh[1024 + c];
        a.l0[(size_t)(rbase + rg * 2 + 0) * 1024 + c] = acc0[cc] + bias;
        a.l0[(size_t)(rbase + rg * 2 + 1) * 1024 + c] = acc1[cc] + bias;
      }
    }
  }
}

// ===========================================================================
// Decoder: 256 blocks = 64 ntile(8n) x 4 btile(32b, 2 cohorts of 16).
// Full weight residency = 112 VGPRs/thread (28 float4).
// ===========================================================================
__device__ __forceinline__ void dec_phase(const Args& a, float* sm, int bx, int tid) {
  const int ntile = bx >> 2, btile = bx & 3;
  const int n0 = ntile * 8, b0 = btile * 32;
  const int kc = tid & 31, ng = tid >> 5;         // compute: 8 n-rows x 32 k-slices
  const int rA = n0 + ng;
  const int rb = tid >> 3, rn = tid & 7;          // reducer (tid<128): PART row = tid
  const int j5 = tid & 31, hw8 = tid >> 5;        // head roles
  float* HOLD = sm;            // 16*576 = 9216
  float* HIN  = sm + 9216;     // 16*576
  float* PART = sm + 18432;    // 128*36 = 4608
  float* XIN  = sm + 23040;    // 32*4

  float4 V0[4], V1[8], V2[8], V3[8];
  {
    const float4* p = (const float4*)(a.dWhh + (size_t)rA * H + kc * 16);
#pragma unroll
    for (int i = 0; i < 4; i++) V0[i] = p[i];
    const float* s1;
    s1 = (kc < 16) ? (a.dWihr + (size_t)rA * H + kc * 32)
                   : (a.dWhh + ((size_t)H + rA) * H + (kc - 16) * 32);
    p = (const float4*)s1;
#pragma unroll
    for (int i = 0; i < 8; i++) V1[i] = p[i];
    s1 = (kc < 16) ? (a.dWihr + ((size_t)H + rA) * H + kc * 32)
                   : (a.dWhh + ((size_t)2 * H + rA) * H + (kc - 16) * 32);
    p = (const float4*)s1;
#pragma unroll
    for (int i = 0; i < 8; i++) V2[i] = p[i];
    s1 = (kc < 16) ? (a.dWihr + ((size_t)2 * H + rA) * H + kc * 32)
                   : (a.dWhh + ((size_t)3 * H + rA) * H + (kc - 16) * 32);
    p = (const float4*)s1;
#pragma unroll
    for (int i = 0; i < 8; i++) V3[i] = p[i];
  }
  float bsl[4];
#pragma unroll
  for (int l = 0; l < 4; l++) bsl[l] = a.dbih[l * H + n0 + rn] + a.dbhh[l * H + n0 + rn];
  float wx0 = a.dWih0[(n0 + rn) * 3 + 0];
  float wx1 = a.dWih0[(n0 + rn) * 3 + 1];
  float wx2 = a.dWih0[(n0 + rn) * 3 + 2];
  float4 LW[4];
  {
    const float4* lw = (const float4*)a.linW;
#pragma unroll
    for (int i = 0; i < 4; i++) LW[i] = lw[j5 * 4 + i];
  }
  float lb0 = a.linb[0];
  if (tid < 32) {
    const float* xr = a.x + (size_t)(b0 + tid) * 384 + 381;
    XIN[tid * 4 + 0] = xr[0]; XIN[tid * 4 + 1] = xr[1];
    XIN[tid * 4 + 2] = xr[2]; XIN[tid * 4 + 3] = 0.f;
  }

  for (int s = 0; s <= TGT; s++) {
    const int p = s & 1, q = 1 - p;
    const int lmax = (s == TGT) ? 1 : 4;
    for (int l = 0; l < lmax; l++) {
      for (int coh = 0; coh < 2; coh++) {
        unsigned* c = a.ctr + (64 + btile * 2 + coh) * 32;
        const unsigned stg = (unsigned)(s * 4 + l);
        if (stg) waitc(c, 64u * stg); else __syncthreads();
        const int cb0 = coh * 16;
        {
          int row = tid >> 4, seg = tid & 15;   // 16 rows x 16 chunks of 32 floats
          if (s < TGT) {
            const float4* gp = (const float4*)(a.dst + ((size_t)(p * 4 + l) * B + b0 + cb0 + row) * H + seg * 32);
            float4* lp = (float4*)(HOLD + row * 576 + seg * 36);
#pragma unroll
            for (int i = 0; i < 8; i++) lp[i] = gp[i];
          }
          const float* gsrc = nullptr;
          if (l > 0)      gsrc = a.dst + ((size_t)(q * 4 + (l - 1)) * B + b0 + cb0 + row) * H;
          else if (s > 0) gsrc = a.dst + ((size_t)(p * 4 + 3) * B + b0 + cb0 + row) * H;
          if (gsrc) {
            const float4* gp = (const float4*)(gsrc + seg * 32);
            float4* lp = (float4*)(HIN + row * 576 + seg * 36);
#pragma unroll
            for (int i = 0; i < 8; i++) lp[i] = gp[i];
          }
        }
        __syncthreads();
        if (l == 0) {
          if (s > 0) {
#pragma unroll
            for (int pass = 0; pass < 2; pass++) {
              int lrow = hw8 + pass * 8;
              int row = cb0 + lrow;
              const float4* h4 = (const float4*)(HIN + lrow * 576 + (j5 >> 1) * 36 + (j5 & 1) * 16);
              float v = d4(h4[0], LW[0]) + d4(h4[1], LW[1]) + d4(h4[2], LW[2]) + d4(h4[3], LW[3]);
              v += __shfl_xor(v, 16); v += __shfl_xor(v, 8);
              v += __shfl_xor(v, 4);  v += __shfl_xor(v, 2); v += __shfl_xor(v, 1);
              if (j5 == 0) {
                float o0 = v + lb0;
                float s1v = XIN[row * 4 + 0] - o0;
                float s2v = XIN[row * 4 + 1] - s1v;
                XIN[row * 4 + 0] = o0; XIN[row * 4 + 1] = s1v; XIN[row * 4 + 2] = s2v;
                if (ntile == 0) a.out[(size_t)(b0 + row) * TGT + (s - 1)] = o0;
              }
            }
          }
          __syncthreads();
        }
        if (s == TGT) continue;
        {
          for (int b = 0; b < 16; b++) {
            float a0 = 0.f;
            if (l == 0) {
              const float4* h4 = (const float4*)(HOLD + b * 576 + (kc >> 1) * 36 + (kc & 1) * 16);
#pragma unroll
              for (int i = 0; i < 4; i++) a0 += d4(V0[i], h4[i]);
            } else {
              const float4* h4 = (const float4*)(((kc < 16) ? HIN : HOLD) + b * 576 + (kc & 15) * 36);
              if (l == 1) {
#pragma unroll
                for (int i = 0; i < 8; i++) a0 += d4(V1[i], h4[i]);
              } else if (l == 2) {
#pragma unroll
                for (int i = 0; i < 8; i++) a0 += d4(V2[i], h4[i]);
              } else {
#pragma unroll
                for (int i = 0; i < 8; i++) a0 += d4(V3[i], h4[i]);
              }
            }
            PART[(b * 8 + ng) * 36 + kc] = a0;
          }
        }
        __syncthreads();
        if (tid < 128) {
          const float4* pp = (const float4*)(PART + tid * 36);
          float sum = 0.f;
#pragma unroll
          for (int i = 0; i < 8; i++) sum += (pp[i].x + pp[i].y) + (pp[i].z + pp[i].w);
          float pre = sum + bsl[l];
          if (l == 0)
            pre += XIN[(cb0 + rb) * 4 + 0] * wx0 + XIN[(cb0 + rb) * 4 + 1] * wx1
                 + XIN[(cb0 + rb) * 4 + 2] * wx2;
          float o = tanhf(pre);
          a.dst[((size_t)(q * 4 + l) * B + b0 + cb0 + rb) * H + n0 + rn] = o;
        }
        bump(c);
      }
    }
  }
}

// ===========================================================================
__global__ __launch_bounds__(256, 1) void birnn_all(Args a) {
  __shared__ __align__(16) float sm[33024];
  const int tid = threadIdx.x, bx = blockIdx.x;
  enc_phase<false>(a, sm, bx, tid);
  { unsigned* g = a.ctr + 96 * 32; bump(g); waitc(g, 256u); }
  proj_phase(a, sm, bx, tid);
  { unsigned* g = a.ctr + 96 * 32; bump(g); waitc(g, 512u); }
  enc_phase<true>(a, sm, bx, tid);
  { unsigned* g = a.ctr + 96 * 32; bump(g); waitc(g, 768u); }
  dec_phase(a, sm, bx, tid);
}

// ---------------------------------------------------------------------------
extern "C" void kernel_launch(void* const* d_in, const int* in_sizes, int n_in,
                              void* d_out, int out_size, void* d_ws, size_t ws_size,
                              hipStream_t stream) {
  float* dst = (float*)d_ws;
  unsigned* ctr = (unsigned*)((char*)d_ws + 2097152);
  float* l0 = (float*)((char*)d_ws + 2097152 + 16384);

  kinit<<<256, 256, 0, stream>>>(dst, ctr);

  Args args;
  args.x = (const float*)d_in[0];
  args.eWih0 = (const float*)d_in[2];
  args.eWhh0 = (const float*)d_in[3];
  args.eWih1 = (const float*)d_in[4];
  args.eWhh1 = (const float*)d_in[5];
  args.ebih = (const float*)d_in[6];
  args.ebhh = (const float*)d_in[7];
  args.dWih0 = (const float*)d_in[8];
  args.dWihr = (const float*)d_in[9];
  args.dWhh = (const float*)d_in[10];
  args.dbih = (const float*)d_in[11];
  args.dbhh = (const float*)d_in[12];
  args.linW = (const float*)d_in[13];
  args.linb = (const float*)d_in[14];
  args.dst = dst; args.l0 = l0; args.ctr = ctr;
  args.out = (float*)d_out;

  void* kp[] = { &args };
  hipError_t err = hipLaunchCooperativeKernel((void*)birnn_all, dim3(256), dim3(256),
                                              kp, 0, stream);
  if (err != hipSuccess) {
    // my sync uses raw device-scope atomics (no cooperative-groups API); with
    // 132KB LDS forcing 1 block/CU, 256 blocks co-reside on 256 CUs.
    birnn_all<<<dim3(256), dim3(256), 0, stream>>>(args);
  }
}